// Round 5
// baseline (671.379 us; speedup 1.0000x reference)
//
#include <hip/hip_runtime.h>
#include <hip/hip_bf16.h>
#include <math.h>
#include <stdint.h>

#define D_MODEL 1024
#define NH 16
#define HD 64
#define BATCH 4
#define SEQ 2048

typedef unsigned short u16;
typedef __attribute__((ext_vector_type(4))) unsigned short u16x4;
typedef __attribute__((ext_vector_type(8))) unsigned short u16x8;
typedef __attribute__((ext_vector_type(8))) short short8;
typedef __attribute__((ext_vector_type(4))) float f32x4;

// ---------------------------------------------------------------------------
// fp32 <-> bf16 bits (RNE)
// ---------------------------------------------------------------------------
__device__ __forceinline__ u16 f2bf(float f) {
  uint32_t u = __float_as_uint(f);
  uint32_t r = (u + 0x7FFFu + ((u >> 16) & 1u)) >> 16;
  return (u16)r;
}
__device__ __forceinline__ float bf2f(u16 h) {
  return __uint_as_float(((uint32_t)h) << 16);
}

// global -> LDS direct copy, 16B per lane (lds dest = wave-uniform base + lane*16)
__device__ __forceinline__ void gload_lds16(const void* g, void* l) {
  auto gp = (const __attribute__((address_space(1))) uint32_t*)(uintptr_t)(g);
  auto lp = (__attribute__((address_space(3))) uint32_t*)(uintptr_t)(l);
  __builtin_amdgcn_global_load_lds(gp, lp, 16, 0, 0);
}

// ---------------------------------------------------------------------------
// split fp32 -> bf16 hi/lo   (lo = bf16(x - f32(hi)))
// ---------------------------------------------------------------------------
__launch_bounds__(256)
__global__ void split_hl(const float* __restrict__ in, u16* __restrict__ hi,
                         u16* __restrict__ lo, int n4) {
  int i = blockIdx.x * blockDim.x + threadIdx.x;
  const int stride = gridDim.x * blockDim.x;
  for (; i < n4; i += stride) {
    float4 v = ((const float4*)in)[i];
    u16x4 h, l4;
    h.x = f2bf(v.x); l4.x = f2bf(v.x - bf2f(h.x));
    h.y = f2bf(v.y); l4.y = f2bf(v.y - bf2f(h.y));
    h.z = f2bf(v.z); l4.z = f2bf(v.z - bf2f(h.z));
    h.w = f2bf(v.w); l4.w = f2bf(v.w - bf2f(h.w));
    ((u16x4*)hi)[i] = h;
    ((u16x4*)lo)[i] = l4;
  }
}

// ---------------------------------------------------------------------------
// C[M,N] = A[M,K] @ B[N,K]^T, split-bf16 x3 MFMA (fp32-accurate):
//   C = Ahi*Bhi + Ahi*Blo + Alo*Bhi   (drops only lo*lo, ~2^-16 rel)
// 128x128 tile, BK=32, 4 waves (m97 structure). SPLIT=1: emit hi/lo bf16.
// ---------------------------------------------------------------------------
template <int SPLIT>
__launch_bounds__(256)
__global__ void gemm_nt_bf16x3(const u16* __restrict__ Ahi, const u16* __restrict__ Alo,
                               const u16* __restrict__ Bhi, const u16* __restrict__ Blo,
                               float* __restrict__ C, u16* __restrict__ Chi,
                               u16* __restrict__ Clo, int M, int N, int K) {
  __shared__ u16 sAh[128][32];
  __shared__ u16 sAl[128][32];
  __shared__ u16 sBh[128][32];
  __shared__ u16 sBl[128][32];

  const int tid = threadIdx.x;
  const int w = tid >> 6;
  const int l = tid & 63;
  const int bm = blockIdx.y * 128;
  const int bn = blockIdx.x * 128;
  const int wr = (w >> 1) * 64;
  const int wc = (w & 1) * 64;

  const int lr = l >> 2;          // lane covers row bo/64 + lr
  const int lco = (l & 3) << 3;   // and cols lco..lco+7 (16B)

  const u16* gAh = Ahi + (size_t)bm * K;
  const u16* gAl = Alo + (size_t)bm * K;
  const u16* gBh = Bhi + (size_t)bn * K;
  const u16* gBl = Blo + (size_t)bn * K;

  f32x4 acc[4][4] = {};

  const int fr = l & 15;
  const int fko = (l >> 4) << 3;

  for (int k0 = 0; k0 < K; k0 += 32) {
    __syncthreads();
#pragma unroll
    for (int i = 0; i < 2; ++i) {
      const int bo = (w + 4 * i) << 10;          // wave-uniform 1KB chunk
      const int r = (bo >> 6) + lr;
      const size_t go = (size_t)r * K + k0 + lco;
      gload_lds16(gAh + go, (char*)&sAh[0][0] + bo);
      gload_lds16(gAl + go, (char*)&sAl[0][0] + bo);
      gload_lds16(gBh + go, (char*)&sBh[0][0] + bo);
      gload_lds16(gBl + go, (char*)&sBl[0][0] + bo);
    }
    __syncthreads();

    short8 ah[4], al[4], bh[4], bl[4];
#pragma unroll
    for (int m = 0; m < 4; ++m) {
      ah[m] = *(const short8*)&sAh[wr + m * 16 + fr][fko];
      al[m] = *(const short8*)&sAl[wr + m * 16 + fr][fko];
    }
#pragma unroll
    for (int n = 0; n < 4; ++n) {
      bh[n] = *(const short8*)&sBh[wc + n * 16 + fr][fko];
      bl[n] = *(const short8*)&sBl[wc + n * 16 + fr][fko];
    }
#pragma unroll
    for (int m = 0; m < 4; ++m)
#pragma unroll
      for (int n = 0; n < 4; ++n) {
        acc[m][n] = __builtin_amdgcn_mfma_f32_16x16x32_bf16(ah[m], bh[n], acc[m][n], 0, 0, 0);
        acc[m][n] = __builtin_amdgcn_mfma_f32_16x16x32_bf16(ah[m], bl[n], acc[m][n], 0, 0, 0);
        acc[m][n] = __builtin_amdgcn_mfma_f32_16x16x32_bf16(al[m], bh[n], acc[m][n], 0, 0, 0);
      }
  }

  // C/D layout: col=lane&15, row=(lane>>4)*4 + j  [m89 verified]
#pragma unroll
  for (int m = 0; m < 4; ++m) {
    const int row0 = bm + wr + m * 16 + ((l >> 4) << 2);
#pragma unroll
    for (int n = 0; n < 4; ++n) {
      const int col = bn + wc + n * 16 + fr;
      f32x4 v = acc[m][n];
      if constexpr (SPLIT) {
#pragma unroll
        for (int j = 0; j < 4; ++j) {
          const size_t idx = (size_t)(row0 + j) * N + col;
          u16 hh = f2bf(v[j]);
          Chi[idx] = hh;
          Clo[idx] = f2bf(v[j] - bf2f(hh));
        }
      } else {
        float* cp = C + (size_t)row0 * N + col;
#pragma unroll
        for (int j = 0; j < 4; ++j) cp[(size_t)j * N] = v[j];
      }
    }
  }
}

// ---------------------------------------------------------------------------
// MFMA causal flash attention on hi/lo bf16 qkv (split-bf16 x3, fp32-accurate).
// 256 threads = 4 waves; 64 queries/block (16/wave); KV tile = 32 keys.
// Swapped QK^T (S^T = K·Q^T) -> softmax stats per q = lane&15, shfl_xor(16|32).
// K LDS [32][64] XOR-swizzled (write & read); V^T [64][40]; P via per-wave LDS.
// Causal-skip is wave-uniform and guarantees j0 <= q0w (no all-masked rows).
// ---------------------------------------------------------------------------
__launch_bounds__(256)
__global__ void attn_mfma(const u16* __restrict__ qkvh, const u16* __restrict__ qkvl,
                          u16* __restrict__ Ohi, u16* __restrict__ Olo) {
  __shared__ u16 Kh[32][64], Kl[32][64];
  __shared__ u16 Vh[64][40], Vl[64][40];
  __shared__ u16 Ph[4][16][40], Pl[4][16][40];

  const int tid = threadIdx.x;
  const int w = tid >> 6, l = tid & 63;
  const int g = l >> 4, q16 = l & 15;
  const int qb = blockIdx.x, bh = blockIdx.y;
  const int b = bh >> 4, h = bh & 15;
  const size_t base = (size_t)b * SEQ * (3 * D_MODEL) + h * HD;  // elements
  const int q0w = qb * 64 + w * 16;

  char* KhB = (char*)&Kh[0][0];
  char* KlB = (char*)&Kl[0][0];
  char* VhB = (char*)&Vh[0][0];
  char* VlB = (char*)&Vl[0][0];
  char* PhB = (char*)&Ph[w][0][0];
  char* PlB = (char*)&Pl[w][0][0];

  // ---- Q B-fragments: lane holds Q[q=l&15][d = dh*32 + 8g + j]
  short8 Qhf[2], Qlf[2];
  {
    const size_t qoff = base + (size_t)(q0w + q16) * (3 * D_MODEL);
#pragma unroll
    for (int dh = 0; dh < 2; ++dh) {
      Qhf[dh] = *(const short8*)(qkvh + qoff + dh * 32 + g * 8);
      Qlf[dh] = *(const short8*)(qkvl + qoff + dh * 32 + g * 8);
    }
  }

  f32x4 acc[4] = {};
  float m_run = -1e30f, l_run = 0.0f;
  const int ktiles = 2 * qb + 2;

  for (int kt = 0; kt < ktiles; ++kt) {
    const int j0 = kt * 32;
    __syncthreads();  // prior tile's LDS reads complete

    // ---- stage K tile [32][64] hi/lo, XOR swizzle ((row&7)<<4) on byte offset
    {
      const int k = tid >> 3, d0 = (tid & 7) * 8;
      const size_t src = base + D_MODEL + (size_t)(j0 + k) * (3 * D_MODEL) + d0;
      u16x8 hv = *(const u16x8*)(qkvh + src);
      u16x8 lv = *(const u16x8*)(qkvl + src);
      const int off = k * 128 + ((d0 * 2) ^ ((k & 7) << 4));
      *(u16x8*)(KhB + off) = hv;
      *(u16x8*)(KlB + off) = lv;
    }
    // ---- stage V^T [64][40] hi/lo (4x4 block transpose; threads 0..127)
    if (tid < 128) {
      const int d0 = (tid >> 3) * 4, k0 = (tid & 7) * 4;
      const size_t src = base + 2 * D_MODEL + (size_t)(j0 + k0) * (3 * D_MODEL) + d0;
      u16x4 h0 = *(const u16x4*)(qkvh + src);
      u16x4 h1 = *(const u16x4*)(qkvh + src + 3 * D_MODEL);
      u16x4 h2 = *(const u16x4*)(qkvh + src + 6 * D_MODEL);
      u16x4 h3 = *(const u16x4*)(qkvh + src + 9 * D_MODEL);
      u16x4 l0 = *(const u16x4*)(qkvl + src);
      u16x4 l1 = *(const u16x4*)(qkvl + src + 3 * D_MODEL);
      u16x4 l2 = *(const u16x4*)(qkvl + src + 6 * D_MODEL);
      u16x4 l3 = *(const u16x4*)(qkvl + src + 9 * D_MODEL);
#pragma unroll
      for (int j = 0; j < 4; ++j) {
        u16x4 th, tl;
        th[0] = h0[j]; th[1] = h1[j]; th[2] = h2[j]; th[3] = h3[j];
        tl[0] = l0[j]; tl[1] = l1[j]; tl[2] = l2[j]; tl[3] = l3[j];
        const int off = (d0 + j) * 80 + k0 * 2;
        *(u16x4*)(VhB + off) = th;
        *(u16x4*)(VlB + off) = tl;
      }
    }
    __syncthreads();

    if (j0 <= q0w + 15) {  // wave-uniform; with 32|j0, 16|q0w this implies j0<=q0w
      // ---- K A-fragments: lane holds K[key=16*t2+q16][d = dh*32 + 8g + j]
      short8 KAh[2][2], KAl[2][2];
#pragma unroll
      for (int t2 = 0; t2 < 2; ++t2)
#pragma unroll
        for (int dh = 0; dh < 2; ++dh) {
          const int row = 16 * t2 + q16;
          const int off = row * 128 + ((dh * 64 + g * 16) ^ ((q16 & 7) << 4));
          KAh[t2][dh] = *(const short8*)(KhB + off);
          KAl[t2][dh] = *(const short8*)(KlB + off);
        }
      // ---- S^T = K·Q^T  (C/D: col=q=l&15, row=key=4g+j within half t2)
      f32x4 S[2] = {};
#pragma unroll
      for (int t2 = 0; t2 < 2; ++t2)
#pragma unroll
        for (int dh = 0; dh < 2; ++dh) {
          S[t2] = __builtin_amdgcn_mfma_f32_16x16x32_bf16(KAh[t2][dh], Qhf[dh], S[t2], 0, 0, 0);
          S[t2] = __builtin_amdgcn_mfma_f32_16x16x32_bf16(KAh[t2][dh], Qlf[dh], S[t2], 0, 0, 0);
          S[t2] = __builtin_amdgcn_mfma_f32_16x16x32_bf16(KAl[t2][dh], Qhf[dh], S[t2], 0, 0, 0);
        }
      // ---- causal mask + 1/sqrt(hd)=0.125 scale + online softmax
      const int qg = q0w + q16;
      float p[8];
      float mx = -1e30f;
#pragma unroll
      for (int t2 = 0; t2 < 2; ++t2)
#pragma unroll
        for (int j = 0; j < 4; ++j) {
          const int kg = j0 + 16 * t2 + 4 * g + j;
          float s = (kg <= qg) ? S[t2][j] * 0.125f : -1e30f;
          p[t2 * 4 + j] = s;
          mx = fmaxf(mx, s);
        }
      mx = fmaxf(mx, __shfl_xor(mx, 16));
      mx = fmaxf(mx, __shfl_xor(mx, 32));
      const float m_new = fmaxf(m_run, mx);
      float sum = 0.f;
#pragma unroll
      for (int i = 0; i < 8; ++i) { p[i] = __expf(p[i] - m_new); sum += p[i]; }
      sum += __shfl_xor(sum, 16);
      sum += __shfl_xor(sum, 32);
      const float alpha = __expf(m_run - m_new);
      m_run = m_new;
      l_run = l_run * alpha + sum;
      // ---- P hi/lo -> per-wave LDS: row q=q16, keys 16*t2 + 4g + {0..3}
#pragma unroll
      for (int t2 = 0; t2 < 2; ++t2) {
        u16x4 ph, pl;
#pragma unroll
        for (int j = 0; j < 4; ++j) {
          float v = p[t2 * 4 + j];
          ph[j] = f2bf(v);
          pl[j] = f2bf(v - bf2f(ph[j]));
        }
        const int off = q16 * 80 + (16 * t2 + 4 * g) * 2;
        *(u16x4*)(PhB + off) = ph;
        *(u16x4*)(PlB + off) = pl;
      }
      // ---- rescale acc (acc[n][j] is row q=4g+j; its stats live in lane 4g+j)
      float al4[4];
#pragma unroll
      for (int j = 0; j < 4; ++j) al4[j] = __shfl(alpha, 4 * g + j);
#pragma unroll
      for (int n = 0; n < 4; ++n) {
        f32x4 t = acc[n];
        t[0] *= al4[0]; t[1] *= al4[1]; t[2] *= al4[2]; t[3] *= al4[3];
        acc[n] = t;
      }
      // ---- PV: A = P[q=l&15][k=8g+j], B = V^T[d=16n+q16][k=8g+j]
      const short8 PAh = *(const short8*)(PhB + q16 * 80 + g * 16);
      const short8 PAl = *(const short8*)(PlB + q16 * 80 + g * 16);
#pragma unroll
      for (int n = 0; n < 4; ++n) {
        const int off = (16 * n + q16) * 80 + g * 16;
        const short8 VBh = *(const short8*)(VhB + off);
        const short8 VBl = *(const short8*)(VlB + off);
        acc[n] = __builtin_amdgcn_mfma_f32_16x16x32_bf16(PAh, VBh, acc[n], 0, 0, 0);
        acc[n] = __builtin_amdgcn_mfma_f32_16x16x32_bf16(PAh, VBl, acc[n], 0, 0, 0);
        acc[n] = __builtin_amdgcn_mfma_f32_16x16x32_bf16(PAl, VBh, acc[n], 0, 0, 0);
      }
    }
  }

  // ---- epilogue: normalize, emit hi/lo (O[q=4g+j][d=16n+q16])
  float inv[4];
#pragma unroll
  for (int j = 0; j < 4; ++j) inv[j] = 1.0f / __shfl(l_run, 4 * g + j);
#pragma unroll
  for (int n = 0; n < 4; ++n)
#pragma unroll
    for (int j = 0; j < 4; ++j) {
      const size_t idx =
          ((size_t)b * SEQ + q0w + 4 * g + j) * D_MODEL + h * HD + n * 16 + q16;
      const float v = acc[n][j] * inv[j];
      const u16 hh = f2bf(v);
      Ohi[idx] = hh;
      Olo[idx] = f2bf(v - bf2f(hh));
    }
}

// ---------------------------------------------------------------------------
extern "C" void kernel_launch(void* const* d_in, const int* in_sizes, int n_in,
                              void* d_out, int out_size, void* d_ws, size_t ws_size,
                              hipStream_t stream) {
  const float* x    = (const float*)d_in[0];   // [4,2048,1024]
  const float* Wqkv = (const float*)d_in[1];   // [3072,1024]
  const float* Wout = (const float*)d_in[2];   // [1024,1024]
  float* out = (float*)d_out;                  // [4,2048,1024]

  const int M = BATCH * SEQ;                   // 8192
  const int N1 = 3 * D_MODEL;                  // 3072
  const size_t MB = 1024 * 1024;

  // workspace layout (144 MB, with aliasing):
  char* ws = (char*)d_ws;
  u16* qkvh = (u16*)(ws);                      // [0,48)   MB
  u16* qkvl = (u16*)(ws + 48 * MB);            // [48,96)
  u16* xhi  = (u16*)(ws + 96 * MB);            // [96,112)
  u16* xlo  = (u16*)(ws + 112 * MB);           // [112,128)
  u16* whi  = (u16*)(ws + 128 * MB);           // [128,134)
  u16* wlo  = (u16*)(ws + 134 * MB);           // [134,140)
  u16* ohi  = (u16*)(ws + 140 * MB);           // [140,142)
  u16* olo  = (u16*)(ws + 142 * MB);           // [142,144)
  // attention output hi/lo alias xhi/xlo (dead after GEMM1):
  u16* ahi  = (u16*)(ws + 96 * MB);
  u16* alo  = (u16*)(ws + 112 * MB);

  // 1) split inputs to bf16 hi/lo
  split_hl<<<2048, 256, 0, stream>>>(x,    xhi, xlo, M * D_MODEL / 4);
  split_hl<<<2048, 256, 0, stream>>>(Wqkv, whi, wlo, N1 * D_MODEL / 4);
  split_hl<<<1024, 256, 0, stream>>>(Wout, ohi, olo, D_MODEL * D_MODEL / 4);

  // 2) qkv(hi/lo) = x @ Wqkv^T   (emit split directly from fp32 accumulator)
  gemm_nt_bf16x3<1><<<dim3(N1 / 128, M / 128), 256, 0, stream>>>(
      xhi, xlo, whi, wlo, nullptr, qkvh, qkvl, M, N1, D_MODEL);

  // 3) causal MFMA flash attention (hi/lo in, hi/lo out)
  attn_mfma<<<dim3(SEQ / 64, BATCH * NH), 256, 0, stream>>>(qkvh, qkvl, ahi, alo);

  // 4) out = attn @ Wout^T  (fp32 out)
  gemm_nt_bf16x3<0><<<dim3(D_MODEL / 128, M / 128), 256, 0, stream>>>(
      ahi, alo, ohi, olo, out, nullptr, nullptr, M, D_MODEL, D_MODEL);
}

// Round 6
// 533.785 us; speedup vs baseline: 1.2578x; 1.2578x over previous
//
#include <hip/hip_runtime.h>
#include <hip/hip_bf16.h>
#include <math.h>
#include <stdint.h>

#define D_MODEL 1024
#define NH 16
#define HD 64
#define BATCH 4
#define SEQ 2048

typedef unsigned short u16;
typedef __attribute__((ext_vector_type(2))) unsigned short u16x2;
typedef __attribute__((ext_vector_type(4))) unsigned short u16x4;
typedef __attribute__((ext_vector_type(8))) unsigned short u16x8;
typedef __attribute__((ext_vector_type(8))) short short8;
typedef __attribute__((ext_vector_type(4))) float f32x4;

// ---------------------------------------------------------------------------
// fp32 <-> bf16 bits (RNE) — branchless manual (header impl may branch)
// ---------------------------------------------------------------------------
__device__ __forceinline__ u16 f2bf(float f) {
  uint32_t u = __float_as_uint(f);
  uint32_t r = (u + 0x7FFFu + ((u >> 16) & 1u)) >> 16;
  return (u16)r;
}
__device__ __forceinline__ float bf2f(u16 h) {
  return __uint_as_float(((uint32_t)h) << 16);
}

// global -> LDS direct copy, 16B per lane (lds dest = wave-uniform base + lane*16)
__device__ __forceinline__ void gload_lds16(const void* g, void* l) {
  auto gp = (const __attribute__((address_space(1))) uint32_t*)(uintptr_t)(g);
  auto lp = (__attribute__((address_space(3))) uint32_t*)(uintptr_t)(l);
  __builtin_amdgcn_global_load_lds(gp, lp, 16, 0, 0);
}

// ---------------------------------------------------------------------------
// split fp32 -> bf16 hi/lo   (lo = bf16(x - f32(hi)))
// ---------------------------------------------------------------------------
__launch_bounds__(256)
__global__ void split_hl(const float* __restrict__ in, u16* __restrict__ hi,
                         u16* __restrict__ lo, int n4) {
  int i = blockIdx.x * blockDim.x + threadIdx.x;
  const int stride = gridDim.x * blockDim.x;
  for (; i < n4; i += stride) {
    float4 v = ((const float4*)in)[i];
    u16x4 h, l4;
    h.x = f2bf(v.x); l4.x = f2bf(v.x - bf2f(h.x));
    h.y = f2bf(v.y); l4.y = f2bf(v.y - bf2f(h.y));
    h.z = f2bf(v.z); l4.z = f2bf(v.z - bf2f(h.z));
    h.w = f2bf(v.w); l4.w = f2bf(v.w - bf2f(h.w));
    ((u16x4*)hi)[i] = h;
    ((u16x4*)lo)[i] = l4;
  }
}

// ---------------------------------------------------------------------------
// C[M,N] = A[M,K] @ B[N,K]^T, split-bf16 x3 MFMA (fp32-accurate):
//   C = Ahi*Bhi + Ahi*Blo + Alo*Bhi   (drops only lo*lo, ~2^-16 rel)
// 128x128 tile, BK=32, 4 waves (m97 structure). SPLIT=1: emit hi/lo bf16.
// FROZEN since round 4 (running at ~m97 ceiling per round-5 counters).
// ---------------------------------------------------------------------------
template <int SPLIT>
__launch_bounds__(256)
__global__ void gemm_nt_bf16x3(const u16* __restrict__ Ahi, const u16* __restrict__ Alo,
                               const u16* __restrict__ Bhi, const u16* __restrict__ Blo,
                               float* __restrict__ C, u16* __restrict__ Chi,
                               u16* __restrict__ Clo, int M, int N, int K) {
  __shared__ u16 sAh[128][32];
  __shared__ u16 sAl[128][32];
  __shared__ u16 sBh[128][32];
  __shared__ u16 sBl[128][32];

  const int tid = threadIdx.x;
  const int w = tid >> 6;
  const int l = tid & 63;
  const int bm = blockIdx.y * 128;
  const int bn = blockIdx.x * 128;
  const int wr = (w >> 1) * 64;
  const int wc = (w & 1) * 64;

  const int lr = l >> 2;
  const int lco = (l & 3) << 3;

  const u16* gAh = Ahi + (size_t)bm * K;
  const u16* gAl = Alo + (size_t)bm * K;
  const u16* gBh = Bhi + (size_t)bn * K;
  const u16* gBl = Blo + (size_t)bn * K;

  f32x4 acc[4][4] = {};

  const int fr = l & 15;
  const int fko = (l >> 4) << 3;

  for (int k0 = 0; k0 < K; k0 += 32) {
    __syncthreads();
#pragma unroll
    for (int i = 0; i < 2; ++i) {
      const int bo = (w + 4 * i) << 10;
      const int r = (bo >> 6) + lr;
      const size_t go = (size_t)r * K + k0 + lco;
      gload_lds16(gAh + go, (char*)&sAh[0][0] + bo);
      gload_lds16(gAl + go, (char*)&sAl[0][0] + bo);
      gload_lds16(gBh + go, (char*)&sBh[0][0] + bo);
      gload_lds16(gBl + go, (char*)&sBl[0][0] + bo);
    }
    __syncthreads();

    short8 ah[4], al[4], bh[4], bl[4];
#pragma unroll
    for (int m = 0; m < 4; ++m) {
      ah[m] = *(const short8*)&sAh[wr + m * 16 + fr][fko];
      al[m] = *(const short8*)&sAl[wr + m * 16 + fr][fko];
    }
#pragma unroll
    for (int n = 0; n < 4; ++n) {
      bh[n] = *(const short8*)&sBh[wc + n * 16 + fr][fko];
      bl[n] = *(const short8*)&sBl[wc + n * 16 + fr][fko];
    }
#pragma unroll
    for (int m = 0; m < 4; ++m)
#pragma unroll
      for (int n = 0; n < 4; ++n) {
        acc[m][n] = __builtin_amdgcn_mfma_f32_16x16x32_bf16(ah[m], bh[n], acc[m][n], 0, 0, 0);
        acc[m][n] = __builtin_amdgcn_mfma_f32_16x16x32_bf16(ah[m], bl[n], acc[m][n], 0, 0, 0);
        acc[m][n] = __builtin_amdgcn_mfma_f32_16x16x32_bf16(al[m], bh[n], acc[m][n], 0, 0, 0);
      }
  }

  // C/D layout: col=lane&15, row=(lane>>4)*4 + j  [m89 verified]
#pragma unroll
  for (int m = 0; m < 4; ++m) {
    const int row0 = bm + wr + m * 16 + ((l >> 4) << 2);
#pragma unroll
    for (int n = 0; n < 4; ++n) {
      const int col = bn + wc + n * 16 + fr;
      f32x4 v = acc[m][n];
      if constexpr (SPLIT) {
#pragma unroll
        for (int j = 0; j < 4; ++j) {
          const size_t idx = (size_t)(row0 + j) * N + col;
          u16 hh = f2bf(v[j]);
          Chi[idx] = hh;
          Clo[idx] = f2bf(v[j] - bf2f(hh));
        }
      } else {
        float* cp = C + (size_t)row0 * N + col;
#pragma unroll
        for (int j = 0; j < 4; ++j) cp[(size_t)j * N] = v[j];
      }
    }
  }
}

// ---------------------------------------------------------------------------
// Attention v2: paired q-tiles (qb, 31-qb) share K/V staging; register
// prefetch (issue-early/write-late). Fragment math identical to round 4.
// ---------------------------------------------------------------------------
struct AttnCtx {
  short8 Qh[2], Ql[2];
  f32x4 acc[4];
  float m_run, l_run;
  int q0w;  // first query row owned by this wave in this context
};

__device__ __forceinline__ void ctx_init(AttnCtx& C, const u16* __restrict__ qkvh,
                                         const u16* __restrict__ qkvl, size_t base,
                                         int q0w, int g, int q16) {
  C.q0w = q0w;
  const size_t qoff = base + (size_t)(q0w + q16) * (3 * D_MODEL);
#pragma unroll
  for (int dh = 0; dh < 2; ++dh) {
    C.Qh[dh] = *(const short8*)(qkvh + qoff + dh * 32 + g * 8);
    C.Ql[dh] = *(const short8*)(qkvl + qoff + dh * 32 + g * 8);
  }
#pragma unroll
  for (int n = 0; n < 4; ++n) C.acc[n] = f32x4{0.f, 0.f, 0.f, 0.f};
  C.m_run = -1e30f;
  C.l_run = 0.f;
}

__device__ __forceinline__ void process_tile(AttnCtx& C, int j0, int g, int q16,
                                             const char* KhB, const char* KlB,
                                             const char* VhB, const char* VlB,
                                             char* PhB, char* PlB) {
  // ---- K A-fragments: lane holds K[key=16*t2+q16][d = dh*32 + 8g + j]
  short8 KAh[2][2], KAl[2][2];
#pragma unroll
  for (int t2 = 0; t2 < 2; ++t2)
#pragma unroll
    for (int dh = 0; dh < 2; ++dh) {
      const int row = 16 * t2 + q16;
      const int off = row * 128 + ((dh * 64 + g * 16) ^ ((q16 & 7) << 4));
      KAh[t2][dh] = *(const short8*)(KhB + off);
      KAl[t2][dh] = *(const short8*)(KlB + off);
    }
  // ---- S^T = K·Q^T  (C/D: col=q=l&15, row=key=4g+j within half t2)
  f32x4 S[2] = {};
#pragma unroll
  for (int t2 = 0; t2 < 2; ++t2)
#pragma unroll
    for (int dh = 0; dh < 2; ++dh) {
      S[t2] = __builtin_amdgcn_mfma_f32_16x16x32_bf16(KAh[t2][dh], C.Qh[dh], S[t2], 0, 0, 0);
      S[t2] = __builtin_amdgcn_mfma_f32_16x16x32_bf16(KAh[t2][dh], C.Ql[dh], S[t2], 0, 0, 0);
      S[t2] = __builtin_amdgcn_mfma_f32_16x16x32_bf16(KAl[t2][dh], C.Qh[dh], S[t2], 0, 0, 0);
    }
  // ---- causal mask + 1/sqrt(hd)=0.125 scale + online softmax
  const int qg = C.q0w + q16;
  float p[8];
  float mx = -1e30f;
#pragma unroll
  for (int t2 = 0; t2 < 2; ++t2)
#pragma unroll
    for (int j = 0; j < 4; ++j) {
      const int kg = j0 + 16 * t2 + 4 * g + j;
      float s = (kg <= qg) ? S[t2][j] * 0.125f : -1e30f;
      p[t2 * 4 + j] = s;
      mx = fmaxf(mx, s);
    }
  mx = fmaxf(mx, __shfl_xor(mx, 16));
  mx = fmaxf(mx, __shfl_xor(mx, 32));
  const float m_new = fmaxf(C.m_run, mx);
  float sum = 0.f;
#pragma unroll
  for (int i = 0; i < 8; ++i) { p[i] = __expf(p[i] - m_new); sum += p[i]; }
  sum += __shfl_xor(sum, 16);
  sum += __shfl_xor(sum, 32);
  const float alpha = __expf(C.m_run - m_new);
  C.m_run = m_new;
  C.l_run = C.l_run * alpha + sum;
  // ---- P hi/lo -> per-wave LDS: row q=q16, keys 16*t2 + 4g + {0..3}
#pragma unroll
  for (int t2 = 0; t2 < 2; ++t2) {
    u16x4 ph, pl;
#pragma unroll
    for (int j = 0; j < 4; ++j) {
      float v = p[t2 * 4 + j];
      ph[j] = f2bf(v);
      pl[j] = f2bf(v - bf2f(ph[j]));
    }
    const int off = q16 * 80 + (16 * t2 + 4 * g) * 2;
    *(u16x4*)(PhB + off) = ph;
    *(u16x4*)(PlB + off) = pl;
  }
  // ---- rescale acc (acc[n][j] is row q=4g+j; its stats live in lane 4g+j)
  float al4[4];
#pragma unroll
  for (int j = 0; j < 4; ++j) al4[j] = __shfl(alpha, 4 * g + j);
#pragma unroll
  for (int n = 0; n < 4; ++n) {
    f32x4 t = C.acc[n];
    t[0] *= al4[0]; t[1] *= al4[1]; t[2] *= al4[2]; t[3] *= al4[3];
    C.acc[n] = t;
  }
  // ---- PV: A = P[q=l&15][k=8g+j], B = V^T[d=16n+q16][k=8g+j]
  const short8 PAh = *(const short8*)(PhB + q16 * 80 + g * 16);
  const short8 PAl = *(const short8*)(PlB + q16 * 80 + g * 16);
#pragma unroll
  for (int n = 0; n < 4; ++n) {
    const int off = (16 * n + q16) * 80 + g * 16;
    const short8 VBh = *(const short8*)(VhB + off);
    const short8 VBl = *(const short8*)(VlB + off);
    C.acc[n] = __builtin_amdgcn_mfma_f32_16x16x32_bf16(PAh, VBh, C.acc[n], 0, 0, 0);
    C.acc[n] = __builtin_amdgcn_mfma_f32_16x16x32_bf16(PAh, VBl, C.acc[n], 0, 0, 0);
    C.acc[n] = __builtin_amdgcn_mfma_f32_16x16x32_bf16(PAl, VBh, C.acc[n], 0, 0, 0);
  }
}

__device__ __forceinline__ void ctx_epilogue(const AttnCtx& C, u16* __restrict__ Ohi,
                                             u16* __restrict__ Olo, int b, int h,
                                             int g, int q16) {
  float inv[4];
#pragma unroll
  for (int j = 0; j < 4; ++j) inv[j] = 1.0f / __shfl(C.l_run, 4 * g + j);
#pragma unroll
  for (int n = 0; n < 4; ++n)
#pragma unroll
    for (int j = 0; j < 4; ++j) {
      const size_t idx =
          ((size_t)b * SEQ + C.q0w + 4 * g + j) * D_MODEL + h * HD + n * 16 + q16;
      const float v = C.acc[n][j] * inv[j];
      const u16 hh = f2bf(v);
      Ohi[idx] = hh;
      Olo[idx] = f2bf(v - bf2f(hh));
    }
}

__launch_bounds__(256)
__global__ void attn_mfma(const u16* __restrict__ qkvh, const u16* __restrict__ qkvl,
                          u16* __restrict__ Ohi, u16* __restrict__ Olo) {
  __shared__ u16 Kh[32][64], Kl[32][64];
  __shared__ u16 Vh[64][40], Vl[64][40];
  __shared__ u16 Ph[4][16][40], Pl[4][16][40];

  const int tid = threadIdx.x;
  const int w = tid >> 6, l = tid & 63;
  const int g = l >> 4, q16 = l & 15;
  const int pr = blockIdx.x;            // pair index 0..15
  const int qbA = pr, qbB = 31 - pr;    // balanced pairing: constant total work
  const int bh = blockIdx.y;
  const int b = bh >> 4, h = bh & 15;
  const size_t base = (size_t)b * SEQ * (3 * D_MODEL) + h * HD;  // elements

  char* KhB = (char*)&Kh[0][0];
  char* KlB = (char*)&Kl[0][0];
  char* VhB = (char*)&Vh[0][0];
  char* VlB = (char*)&Vl[0][0];
  char* PhB = (char*)&Ph[w][0][0];
  char* PlB = (char*)&Pl[w][0][0];

  AttnCtx A, B;
  ctx_init(A, qkvh, qkvl, base, qbA * 64 + w * 16, g, q16);
  ctx_init(B, qkvh, qkvl, base, qbB * 64 + w * 16, g, q16);

  // staging geometry
  const int sk = tid >> 3, sd0 = (tid & 7) * 8;         // K: row sk, d sd0..+7
  const int vd0 = (tid & 31) * 2, vk0 = (tid >> 5) * 4; // V: d {vd0,vd0+1}, k vk0..+3
  u16x8 kh_r, kl_r;
  u16x2 vh_r[4], vl_r[4];

  auto loadKV = [&](int j0) {
    const size_t srcK = base + D_MODEL + (size_t)(j0 + sk) * (3 * D_MODEL) + sd0;
    kh_r = *(const u16x8*)(qkvh + srcK);
    kl_r = *(const u16x8*)(qkvl + srcK);
    const size_t srcV = base + 2 * D_MODEL + (size_t)(j0 + vk0) * (3 * D_MODEL) + vd0;
#pragma unroll
    for (int r = 0; r < 4; ++r) {
      vh_r[r] = *(const u16x2*)(qkvh + srcV + (size_t)r * (3 * D_MODEL));
      vl_r[r] = *(const u16x2*)(qkvl + srcV + (size_t)r * (3 * D_MODEL));
    }
  };
  auto writeKV = [&]() {
    const int offK = sk * 128 + ((sd0 * 2) ^ ((sk & 7) << 4));  // XOR swizzle
    *(u16x8*)(KhB + offK) = kh_r;
    *(u16x8*)(KlB + offK) = kl_r;
#pragma unroll
    for (int j = 0; j < 2; ++j) {  // transpose: V^T[d][k]
      u16x4 th, tl;
      th[0] = vh_r[0][j]; th[1] = vh_r[1][j]; th[2] = vh_r[2][j]; th[3] = vh_r[3][j];
      tl[0] = vl_r[0][j]; tl[1] = vl_r[1][j]; tl[2] = vl_r[2][j]; tl[3] = vl_r[3][j];
      const int off = (vd0 + j) * 80 + vk0 * 2;
      *(u16x4*)(VhB + off) = th;
      *(u16x4*)(VlB + off) = tl;
    }
  };

  const int ktiles = 2 * qbB + 2;
  loadKV(0);
  for (int kt = 0; kt < ktiles; ++kt) {
    const int j0 = kt * 32;
    __syncthreads();                       // prior tile's LDS reads done
    writeKV();                             // regs -> LDS (vmcnt waited here)
    __syncthreads();                       // tile visible
    if (kt + 1 < ktiles) loadKV((kt + 1) * 32);  // prefetch next (overlaps compute)
    if (j0 <= B.q0w + 15) process_tile(B, j0, g, q16, KhB, KlB, VhB, VlB, PhB, PlB);
    if (j0 <= A.q0w + 15) process_tile(A, j0, g, q16, KhB, KlB, VhB, VlB, PhB, PlB);
  }

  ctx_epilogue(B, Ohi, Olo, b, h, g, q16);
  ctx_epilogue(A, Ohi, Olo, b, h, g, q16);
}

// ---------------------------------------------------------------------------
extern "C" void kernel_launch(void* const* d_in, const int* in_sizes, int n_in,
                              void* d_out, int out_size, void* d_ws, size_t ws_size,
                              hipStream_t stream) {
  const float* x    = (const float*)d_in[0];   // [4,2048,1024]
  const float* Wqkv = (const float*)d_in[1];   // [3072,1024]
  const float* Wout = (const float*)d_in[2];   // [1024,1024]
  float* out = (float*)d_out;                  // [4,2048,1024]

  const int M = BATCH * SEQ;                   // 8192
  const int N1 = 3 * D_MODEL;                  // 3072
  const size_t MB = 1024 * 1024;

  // workspace layout (144 MB, with aliasing):
  char* ws = (char*)d_ws;
  u16* qkvh = (u16*)(ws);                      // [0,48)   MB
  u16* qkvl = (u16*)(ws + 48 * MB);            // [48,96)
  u16* xhi  = (u16*)(ws + 96 * MB);            // [96,112)
  u16* xlo  = (u16*)(ws + 112 * MB);           // [112,128)
  u16* whi  = (u16*)(ws + 128 * MB);           // [128,134)
  u16* wlo  = (u16*)(ws + 134 * MB);           // [134,140)
  u16* ohi  = (u16*)(ws + 140 * MB);           // [140,142)
  u16* olo  = (u16*)(ws + 142 * MB);           // [142,144)
  // attention output hi/lo alias xhi/xlo (dead after GEMM1):
  u16* ahi  = (u16*)(ws + 96 * MB);
  u16* alo  = (u16*)(ws + 112 * MB);

  // 1) split inputs to bf16 hi/lo
  split_hl<<<2048, 256, 0, stream>>>(x,    xhi, xlo, M * D_MODEL / 4);
  split_hl<<<2048, 256, 0, stream>>>(Wqkv, whi, wlo, N1 * D_MODEL / 4);
  split_hl<<<1024, 256, 0, stream>>>(Wout, ohi, olo, D_MODEL * D_MODEL / 4);

  // 2) qkv(hi/lo) = x @ Wqkv^T   (emit split directly from fp32 accumulator)
  gemm_nt_bf16x3<1><<<dim3(N1 / 128, M / 128), 256, 0, stream>>>(
      xhi, xlo, whi, wlo, nullptr, qkvh, qkvl, M, N1, D_MODEL);

  // 3) causal MFMA flash attention (paired q-tiles, shared staging, prefetch)
  attn_mfma<<<dim3(SEQ / 128, BATCH * NH), 256, 0, stream>>>(qkvh, qkvl, ahi, alo);

  // 4) out = attn @ Wout^T  (fp32 out)
  gemm_nt_bf16x3<0><<<dim3(D_MODEL / 128, M / 128), 256, 0, stream>>>(
      ahi, alo, ohi, olo, out, nullptr, nullptr, M, D_MODEL, D_MODEL);
}